// Round 19
// baseline (247.322 us; speedup 1.0000x reference)
//
#include <hip/hip_runtime.h>
#include <hip/hip_bf16.h>

#define DIMD 384
#define SEQL 4096
#define NBATCH 8
#define NTOK (NBATCH*SEQL)

typedef float f32x4 __attribute__((ext_vector_type(4)));
typedef short s16x8 __attribute__((ext_vector_type(8)));
typedef unsigned short u16;
typedef __hip_bfloat16 bf16;

__device__ __forceinline__ float sigf(float x){ return 1.f/(1.f+__expf(-x)); }

// async global->LDS, 16B per lane. LDS dest must be wave-uniform base + lane*16.
typedef __attribute__((address_space(3))) void lds_void;
typedef const __attribute__((address_space(1))) void glb_void;
__device__ __forceinline__ void gl_lds16(const void* g, void* l) {
  __builtin_amdgcn_global_load_lds((glb_void*)g, (lds_void*)l, 16, 0, 0);
}

// ---------------- workspace layout (bytes) ----------------
#define OFF_LAM   0ul
#define OFF_WQ    4096ul                       // bf16 [1536][384]
#define OFF_CW    (OFF_WQ + 1179648ul)         // bf16 [384][448]
#define OFF_W1T   (OFF_CW + 344064ul)          // bf16 [768][384]
#define OFF_W2T   (OFF_W1T + 589824ul)         // bf16 [384][768]
#define OFF_XC    4194304ul                    // bf16 [32768][384]
#define OFF_Q     (OFF_XC + 25165824ul)        // bf16 [32768][384]
#define OFF_U     (OFF_XC + 50331648ul)        // bf16 [32768][384]
#define OFF_AI    OFF_U                        // bf16 [32768][768] (reuse after u dead)
#define OFF_H     (OFF_U + 50331648ul)         // bf16 [32768][384]
// total = 130,023,424 bytes

// ---------------- prep: weight transposes to [n][k] bf16 ----------------
__global__ void k_prep_w(const float* __restrict__ qw, const float* __restrict__ kw,
                         const float* __restrict__ vw, const float* __restrict__ gw,
                         const float* __restrict__ cw, const float* __restrict__ w1,
                         const float* __restrict__ w2,
                         bf16* __restrict__ wqt, bf16* __restrict__ cwt,
                         bf16* __restrict__ w1t, bf16* __restrict__ w2t) {
  const int total = 589824 + 172032 + 294912 + 294912;
  for (int j = blockIdx.x*blockDim.x + threadIdx.x; j < total; j += gridDim.x*blockDim.x) {
    if (j < 589824) {
      int n = j / 384, k = j % 384;
      int mat = n / 384;
      int np = n % 384;                        // (384 not pow2 -> %, not &)
      const float* W = (mat==0)?qw:(mat==1)?kw:(mat==2)?vw:gw;
      wqt[(size_t)n*384 + k] = __float2bfloat16(W[(size_t)k*384 + np]);
    } else if (j < 589824 + 172032) {
      int jj = j - 589824;
      int o = jj / 448, k = jj % 448;
      int kap = k >> 6, i = k & 63;
      cwt[(size_t)o*448 + k] = __float2bfloat16(cw[((size_t)o*64 + i)*7 + kap]);
    } else if (j < 589824 + 172032 + 294912) {
      int jj = j - (589824 + 172032);
      int n = jj / 384, k = jj % 384;
      w1t[(size_t)n*384 + k] = __float2bfloat16(w1[(size_t)k*768 + n]);
    } else {
      int jj = j - (589824 + 172032 + 294912);
      int n = jj / 768, k = jj % 768;
      w2t[(size_t)n*768 + k] = __float2bfloat16(w2[(size_t)k*384 + n]);
    }
  }
}

__global__ void k_prep_lam(const float* __restrict__ decay, float* __restrict__ lam) {
  __shared__ float red[6];
  int t = threadIdx.x; // 384 threads
  float v = sigf(decay[t]);
  for (int off = 32; off; off >>= 1) v += __shfl_xor(v, off, 64);
  if ((t & 63) == 0) red[t >> 6] = v;
  __syncthreads();
  if (t == 0) {
    float s = 0.f;
    for (int i = 0; i < 6; ++i) s += red[i];
    lam[0] = s * (1.f/384.f);
  }
}

// ---------------- grouped conv (k=7, groups=6) + silu -> xc bf16 ----------------
__global__ __launch_bounds__(256) void k_conv(const float* __restrict__ x, const float* __restrict__ cb,
                                              const bf16* __restrict__ cwt, bf16* __restrict__ xc) {
  int id = blockIdx.x;             // 1536 = 8 b * 32 st * 6 g
  int g = id % 6, st = (id/6) & 31, b = id / 192;
  int s0 = st * 128;
  __shared__ u16 xls[134*72];
  __shared__ u16 wls[64*456];
  int tid = threadIdx.x;
  for (int r0 = 0; r0 < 144; r0 += 16) {
    int row = r0 + (tid >> 4);
    if (row < 134) {
      int col = (tid & 15) * 4;
      int s = s0 - 3 + row;
      float4 v = make_float4(0.f,0.f,0.f,0.f);
      if (s >= 0 && s < SEQL)
        v = *reinterpret_cast<const float4*>(x + ((size_t)(b*SEQL + s))*DIMD + g*64 + col);
      u16* dst = &xls[row*72 + col];
      bf16 t0 = __float2bfloat16(v.x); dst[0] = *reinterpret_cast<u16*>(&t0);
      bf16 t1 = __float2bfloat16(v.y); dst[1] = *reinterpret_cast<u16*>(&t1);
      bf16 t2 = __float2bfloat16(v.z); dst[2] = *reinterpret_cast<u16*>(&t2);
      bf16 t3 = __float2bfloat16(v.w); dst[3] = *reinterpret_cast<u16*>(&t3);
    }
  }
  for (int i0 = 0; i0 < 28672; i0 += 1024) {
    int i = i0 + tid*4;
    int o = i / 448, k = i % 448;
    *reinterpret_cast<uint2*>(&wls[o*456 + k]) =
      *reinterpret_cast<const uint2*>(cwt + ((size_t)(g*64 + o))*448 + k);
  }
  __syncthreads();
  int w = tid >> 6, l = tid & 63, l15 = l & 15, lh = l >> 4;
  f32x4 zz = {0.f,0.f,0.f,0.f};
  f32x4 acc[2][4];
  for (int i=0;i<2;++i) for (int jn=0;jn<4;++jn) acc[i][jn]=zz;
  for (int kap = 0; kap < 7; ++kap) {
#pragma unroll
    for (int ic = 0; ic < 2; ++ic) {
      s16x8 a0 = *reinterpret_cast<const s16x8*>(&xls[(w*32 +  0 + l15 + kap)*72 + ic*32 + lh*8]);
      s16x8 a1 = *reinterpret_cast<const s16x8*>(&xls[(w*32 + 16 + l15 + kap)*72 + ic*32 + lh*8]);
#pragma unroll
      for (int nf = 0; nf < 4; ++nf) {
        s16x8 bfr = *reinterpret_cast<const s16x8*>(&wls[(nf*16 + l15)*456 + kap*64 + ic*32 + lh*8]);
        acc[0][nf] = __builtin_amdgcn_mfma_f32_16x16x32_bf16(a0, bfr, acc[0][nf], 0,0,0);
        acc[1][nf] = __builtin_amdgcn_mfma_f32_16x16x32_bf16(a1, bfr, acc[1][nf], 0,0,0);
      }
    }
  }
#pragma unroll
  for (int nf = 0; nf < 4; ++nf) {
    int ch = g*64 + nf*16 + l15;
    float bias = cb[ch];
#pragma unroll
    for (int mf = 0; mf < 2; ++mf) {
#pragma unroll
      for (int r = 0; r < 4; ++r) {
        int m = w*32 + mf*16 + lh*4 + r;
        float v = acc[mf][nf][r] + bias;
        v = v * sigf(v);
        xc[((size_t)(b*SEQL + s0 + m))*DIMD + ch] = __float2bfloat16(v);
      }
    }
  }
}

// ---------------- fused QKVG GEMM (R17): 8 waves, wave owns (matrix, 16-col half) ------------
__global__ __launch_bounds__(512) void k_qkvg(const bf16* __restrict__ xc, const bf16* __restrict__ wt,
    const float* __restrict__ qb, const float* __restrict__ kb,
    const float* __restrict__ vb, const float* __restrict__ gb,
    bf16* __restrict__ qout, bf16* __restrict__ uout) {
  int raw = blockIdx.x;                       // 3072
  int vv = (raw & 7)*384 + (raw >> 3);        // XCD swizzle
  int mt = vv / 12, ct = vv % 12;
  int m0 = mt*128, c0 = ct*32;
  __shared__ __align__(16) u16 smem[16384];   // 32KB dbuf 2x[128][64] / exchange overlay
  int tid = threadIdx.x, w = tid >> 6, l = tid & 63, l15 = l & 15, lh = l >> 4;
  int mat = w >> 1, ch0 = (w & 1)*16;         // wave's matrix + col-half
  f32x4 zz = {0.f,0.f,0.f,0.f};
  f32x4 acc[8];
#pragma unroll
  for (int i=0;i<8;++i) acc[i]=zz;
  const bf16* bp = wt + ((size_t)(mat*384 + c0 + ch0 + l15))*384 + lh*8;
  s16x8 bc0 = *reinterpret_cast<const s16x8*>(bp);
  s16x8 bc1 = *reinterpret_cast<const s16x8*>(bp + 32);
  s16x8 bn0, bn1;
#pragma unroll
  for (int p = 0; p < 2; ++p) {
    int off16 = p*512 + tid;
    int row = off16 >> 3, slot = off16 & 7;
    int ss = slot ^ (row & 7);
    gl_lds16(xc + ((size_t)(m0+row))*DIMD + ss*8, (char*)smem + off16*16);
  }
  __syncthreads();
  for (int kc = 0; kc < 6; ++kc) {
    const u16* cur = smem + (kc & 1)*8192;
    if (kc < 5) {
      char* nxt = (char*)(smem + ((kc & 1)^1)*8192);
#pragma unroll
      for (int p = 0; p < 2; ++p) {
        int off16 = p*512 + tid;
        int row = off16 >> 3, slot = off16 & 7;
        int ss = slot ^ (row & 7);
        gl_lds16(xc + ((size_t)(m0+row))*DIMD + (kc+1)*64 + ss*8, nxt + off16*16);
      }
      int nb = (kc+1)*64;
      bn0 = *reinterpret_cast<const s16x8*>(bp + nb);
      bn1 = *reinterpret_cast<const s16x8*>(bp + nb + 32);
    }
#pragma unroll
    for (int kk = 0; kk < 2; ++kk) {
      s16x8 curb = kk ? bc1 : bc0;
#pragma unroll
      for (int mf = 0; mf < 8; ++mf) {
        s16x8 af = *reinterpret_cast<const s16x8*>(
            &cur[(mf*16 + l15)*64 + (((kk*4 + lh) ^ (l15 & 7))*8)]);
        acc[mf] = __builtin_amdgcn_mfma_f32_16x16x32_bf16(af, curb, acc[mf], 0,0,0);
      }
    }
    __syncthreads();
    bc0 = bn0; bc1 = bn1;
  }
  const float* bpv = (mat==0)?qb:(mat==1)?kb:(mat==2)?vb:gb;
  float bias = bpv[c0 + ch0 + l15];
  if (mat == 0) {
#pragma unroll
    for (int mf=0;mf<8;++mf)
#pragma unroll
      for (int r=0;r<4;++r) {
        int m = mf*16 + lh*4 + r, c = ch0 + l15;
        qout[((size_t)(m0+m))*DIMD + c0 + c] = __float2bfloat16(acc[mf][r] + bias);
      }
  } else {
    u16* exm = smem + (size_t)(mat-1)*(128*40);
#pragma unroll
    for (int mf=0;mf<8;++mf)
#pragma unroll
      for (int r=0;r<4;++r) {
        int m = mf*16 + lh*4 + r, c = ch0 + l15;
        bf16 t = __float2bfloat16(acc[mf][r] + bias);
        exm[m*40 + c] = *reinterpret_cast<u16*>(&t);
      }
  }
  __syncthreads();
#pragma unroll
  for (int p = 0; p < 8; ++p) {
    int idx = p*512 + tid;
    int m = idx >> 5, c = idx & 31;
    u16 kr = smem[0*(128*40) + m*40 + c];
    u16 vr = smem[1*(128*40) + m*40 + c];
    u16 gr = smem[2*(128*40) + m*40 + c];
    float kvv = __bfloat162float(*reinterpret_cast<bf16*>(&kr));
    float vvv = __bfloat162float(*reinterpret_cast<bf16*>(&vr));
    float gvv = __bfloat162float(*reinterpret_cast<bf16*>(&gr));
    uout[((size_t)(m0+m))*DIMD + c0 + c] = __float2bfloat16(vvv * sigf(gvv) * kvv);
  }
}

// ---------------- decayed cumsum + q*diag + LN1 -> h bf16 (48KB LDS, 3 blocks/CU) -------------
__global__ __launch_bounds__(384) void k_scan(const bf16* __restrict__ u, const bf16* __restrict__ q,
    const float* __restrict__ lam_p, const float* __restrict__ l1g, const float* __restrict__ l1b,
    bf16* __restrict__ h) {
  int b = blockIdx.x >> 5, c = blockIdx.x & 31; // 8 x 32
  int d = threadIdx.x;                          // 384
  float lam = lam_p[0];
  __shared__ float ols[32*384];                 // 48 KB
  __shared__ float lgs[384], lbs[384];
  lgs[d] = l1g[d]; lbs[d] = l1b[d];
  int s0 = c*128;
  size_t base = ((size_t)b*SEQL)*DIMD + d;
  float carry = 0.f;
  int sstart = s0 - 64; if (sstart < 0) sstart = 0;
  for (int s = sstart; s < s0; s += 8) {
    float uv[8];
#pragma unroll
    for (int j = 0; j < 8; ++j) uv[j] = __bfloat162float(u[base + (size_t)(s+j)*DIMD]);
#pragma unroll
    for (int j = 0; j < 8; ++j) carry = carry*lam + uv[j];
  }
  int w = d >> 6, lane = d & 63;
  for (int p = 0; p < 4; ++p) {
    int sb = s0 + p*32;
    __syncthreads();
    for (int it0 = 0; it0 < 32; it0 += 8) {
      float uv[8], qv[8];
#pragma unroll
      for (int j = 0; j < 8; ++j) uv[j] = __bfloat162float(u[base + (size_t)(sb+it0+j)*DIMD]);
#pragma unroll
      for (int j = 0; j < 8; ++j) qv[j] = __bfloat162float(q[base + (size_t)(sb+it0+j)*DIMD]);
#pragma unroll
      for (int j = 0; j < 8; ++j) {
        carry = carry*lam + uv[j];
        ols[(it0+j)*384 + d] = carry * qv[j];
      }
    }
    __syncthreads();
    for (int t = w; t < 32; t += 6) {
      float vv[6]; float s1 = 0.f, s2 = 0.f;
#pragma unroll
      for (int j = 0; j < 6; ++j) {
        vv[j] = ols[t*384 + j*64 + lane];
        s1 += vv[j]; s2 += vv[j]*vv[j];
      }
      for (int off = 32; off; off >>= 1) { s1 += __shfl_xor(s1, off, 64); s2 += __shfl_xor(s2, off, 64); }
      float mean = s1 * (1.f/384.f);
      float var = s2 * (1.f/384.f) - mean*mean;
      float rs = rsqrtf(var + 1e-5f);
      size_t rowo = ((size_t)(b*SEQL + sb + t))*DIMD;
#pragma unroll
      for (int j = 0; j < 6; ++j) {
        int dd = j*64 + lane;
        h[rowo + dd] = __float2bfloat16((vv[j]-mean)*rs*lgs[dd] + lbs[dd]);
      }
    }
  }
}

// ---------------- MLP GEMM1 + silu -> ai bf16 (T3 stage-ahead dbuf, BK=64) --------------
__global__ __launch_bounds__(512) void k_mlp1(const bf16* __restrict__ h, const bf16* __restrict__ w1t,
                                              const float* __restrict__ b1, bf16* __restrict__ ai) {
  int raw = blockIdx.x;                 // 1536
  int vv = (raw & 7)*192 + (raw >> 3);
  int mt = vv / 6, nt = vv % 6;
  int m0 = mt*128, n0 = nt*128;
  __shared__ __align__(16) u16 als[16384];   // 32KB = 2 x [128][64]
  int tid = threadIdx.x, w = tid >> 6, l = tid & 63, l15 = l & 15, lh = l >> 4;
  int wm = (w >> 2)*64, wn = (w & 3)*32;
  f32x4 zz = {0.f,0.f,0.f,0.f};
  f32x4 acc[4][2];
#pragma unroll
  for (int i=0;i<4;++i) for (int jn=0;jn<2;++jn) acc[i][jn]=zz;
  const bf16* bp0 = w1t + ((size_t)(n0 + wn + l15))*384 + lh*8;
  s16x8 bA[2], bB[2];
#pragma unroll
  for (int nf = 0; nf < 2; ++nf)
    bA[nf] = *reinterpret_cast<const s16x8*>(bp0 + (size_t)nf*16*384);
#pragma unroll
  for (int p = 0; p < 2; ++p) {
    int off16 = p*512 + tid;
    int row = off16 >> 3, slot = off16 & 7;
    int ss = slot ^ (row & 7);
    gl_lds16(h + ((size_t)(m0+row))*DIMD + ss*8, (char*)als + off16*16);
  }
  __syncthreads();
  for (int kc = 0; kc < 6; ++kc) {
    const u16* cur = als + (kc & 1)*8192;
    if (kc < 5) {
      char* nxt = (char*)(als + ((kc & 1)^1)*8192);
#pragma unroll
      for (int p = 0; p < 2; ++p) {
        int off16 = p*512 + tid;
        int row = off16 >> 3, slot = off16 & 7;
        int ss = slot ^ (row & 7);
        gl_lds16(h + ((size_t)(m0+row))*DIMD + (kc+1)*64 + ss*8, nxt + off16*16);
      }
    }
#pragma unroll
    for (int kk = 0; kk < 2; ++kk) {
      int nko = (kk == 0) ? (kc*64 + 32) : ((kc < 5) ? (kc+1)*64 : -1);
      if (nko >= 0) {
        if (kk) {
#pragma unroll
          for (int nf = 0; nf < 2; ++nf)
            bA[nf] = *reinterpret_cast<const s16x8*>(bp0 + (size_t)nf*16*384 + nko);
        } else {
#pragma unroll
          for (int nf = 0; nf < 2; ++nf)
            bB[nf] = *reinterpret_cast<const s16x8*>(bp0 + (size_t)nf*16*384 + nko);
        }
      }
#pragma unroll
      for (int mf = 0; mf < 4; ++mf) {
        s16x8 af = *reinterpret_cast<const s16x8*>(
            &cur[(wm + mf*16 + l15)*64 + (((kk*4 + lh) ^ (l15 & 7))*8)]);
#pragma unroll
        for (int nf = 0; nf < 2; ++nf)
          acc[mf][nf] = __builtin_amdgcn_mfma_f32_16x16x32_bf16(
              af, kk ? bB[nf] : bA[nf], acc[mf][nf], 0,0,0);
      }
    }
    __syncthreads();
  }
  float bias[2];
#pragma unroll
  for (int nf = 0; nf < 2; ++nf) bias[nf] = b1[n0 + wn + nf*16 + l15];
#pragma unroll
  for (int mf = 0; mf < 4; ++mf)
#pragma unroll
    for (int nf = 0; nf < 2; ++nf)
#pragma unroll
      for (int r = 0; r < 4; ++r) {
        int m = wm + mf*16 + lh*4 + r, ch = n0 + wn + nf*16 + l15;
        float v = acc[mf][nf][r] + bias[nf];
        v = v * sigf(v);
        ai[(size_t)(m0+m)*768 + ch] = __float2bfloat16(v);
      }
}

// ---------------- fused MLP GEMM2 + bias + residual + LN2 -> out f32 (R19: M=32, grid 1024) ---
// 512 threads (8 waves), M=32/block, grid 1024 -> 3-4 blocks/CU (24-32 waves/CU).
// Wave w owns cols [w*48, w*48+48); x residual issue-early into regs (T14).
__global__ __launch_bounds__(512) void k_mlp2ln(const bf16* __restrict__ ai, const bf16* __restrict__ w2t,
                                                const float* __restrict__ b2, const float* __restrict__ x,
                                                const float* __restrict__ l2g, const float* __restrict__ l2b,
                                                float* __restrict__ out) {
  int raw = blockIdx.x;                 // 1024
  int mt = (raw & 7)*128 + (raw >> 3);  // XCD swizzle
  int m0 = mt*32;
  __shared__ __align__(16) u16 als[8192];     // 16KB = 2 x [32][128]
  __shared__ float pls[8][32][2];             // per-wave row partials (2KB)
  int tid = threadIdx.x, w = tid >> 6, l = tid & 63, l15 = l & 15, lh = l >> 4;
  int wn = w*48;
  f32x4 zz = {0.f,0.f,0.f,0.f};
  f32x4 acc[2][3];
#pragma unroll
  for (int i=0;i<2;++i)
#pragma unroll
    for (int jn=0;jn<3;++jn) acc[i][jn]=zz;
  const bf16* bp0 = w2t + ((size_t)(wn + l15))*768 + lh*8;
  s16x8 bA[3], bB[3];
#pragma unroll
  for (int nf = 0; nf < 3; ++nf)
    bA[nf] = *reinterpret_cast<const s16x8*>(bp0 + (size_t)nf*16*768);
  // prologue: tile 0 -> buf0 (512 chunks of 16B, one iteration)
  {
    int off16 = tid;
    int row = off16 >> 4, slot = off16 & 15;
    int ss = slot ^ (row & 7);
    gl_lds16(ai + ((size_t)(m0+row))*768 + ss*8, (char*)als + off16*16);
  }
  __syncthreads();
  // x issue-early: 24 scattered f32 loads; drained at kc=0's end barrier
  float xpre[2][4][3];
#pragma unroll
  for (int mf = 0; mf < 2; ++mf)
#pragma unroll
    for (int r = 0; r < 4; ++r) {
      int m = mf*16 + lh*4 + r;
      const float* xr = x + (size_t)(m0+m)*DIMD + wn + l15;
#pragma unroll
      for (int nf = 0; nf < 3; ++nf) xpre[mf][r][nf] = xr[nf*16];
    }
  for (int kc = 0; kc < 6; ++kc) {
    const u16* cur = als + (kc & 1)*4096;
    if (kc < 5) {
      char* nxt = (char*)(als + ((kc & 1)^1)*4096);
      int off16 = tid;
      int row = off16 >> 4, slot = off16 & 15;
      int ss = slot ^ (row & 7);
      gl_lds16(ai + ((size_t)(m0+row))*768 + (kc+1)*128 + ss*8, nxt + off16*16);
    }
#pragma unroll
    for (int kk = 0; kk < 4; ++kk) {
      int nko = (kk < 3) ? (kc*128 + (kk+1)*32) : ((kc < 5) ? (kc+1)*128 : -1);
      if (nko >= 0) {
        if (kk & 1) {
#pragma unroll
          for (int nf = 0; nf < 3; ++nf)
            bA[nf] = *reinterpret_cast<const s16x8*>(bp0 + (size_t)nf*16*768 + nko);
        } else {
#pragma unroll
          for (int nf = 0; nf < 3; ++nf)
            bB[nf] = *reinterpret_cast<const s16x8*>(bp0 + (size_t)nf*16*768 + nko);
        }
      }
#pragma unroll
      for (int mf = 0; mf < 2; ++mf) {
        s16x8 af = *reinterpret_cast<const s16x8*>(
            &cur[(mf*16 + l15)*128 + (((kk*4 + lh) ^ (l15 & 7))*8)]);
#pragma unroll
        for (int nf = 0; nf < 3; ++nf)
          acc[mf][nf] = __builtin_amdgcn_mfma_f32_16x16x32_bf16(
              af, (kk & 1) ? bB[nf] : bA[nf], acc[mf][nf], 0,0,0);
      }
    }
    __syncthreads();
  }
  // epilogue: v = acc + b2 + xpre (in regs), row stats, LN, store
  float bias[3];
#pragma unroll
  for (int nf = 0; nf < 3; ++nf) bias[nf] = b2[wn + nf*16 + l15];
#pragma unroll
  for (int mf = 0; mf < 2; ++mf) {
#pragma unroll
    for (int r = 0; r < 4; ++r) {
      int m = mf*16 + lh*4 + r;
      float sa = 0.f, sb = 0.f;
#pragma unroll
      for (int nf = 0; nf < 3; ++nf) {
        float v = acc[mf][nf][r] + bias[nf] + xpre[mf][r][nf];
        acc[mf][nf][r] = v;
        sa += v; sb += v*v;
      }
#pragma unroll
      for (int off = 1; off < 16; off <<= 1) {
        sa += __shfl_xor(sa, off, 16);
        sb += __shfl_xor(sb, off, 16);
      }
      if (l15 == 0) { pls[w][m][0] = sa; pls[w][m][1] = sb; }
    }
  }
  __syncthreads();
  float lg[3], lb[3];
#pragma unroll
  for (int nf = 0; nf < 3; ++nf) { lg[nf] = l2g[wn + nf*16 + l15]; lb[nf] = l2b[wn + nf*16 + l15]; }
#pragma unroll
  for (int mf = 0; mf < 2; ++mf) {
#pragma unroll
    for (int r = 0; r < 4; ++r) {
      int m = mf*16 + lh*4 + r;
      float S1 = 0.f, S2 = 0.f;
#pragma unroll
      for (int ww = 0; ww < 8; ++ww) { S1 += pls[ww][m][0]; S2 += pls[ww][m][1]; }
      float mean = S1 * (1.f/384.f);
      float var = S2 * (1.f/384.f) - mean*mean;
      float rs = rsqrtf(var + 1e-5f);
      float* orow = out + (size_t)(m0+m)*DIMD + wn + l15;
#pragma unroll
      for (int nf = 0; nf < 3; ++nf)
        orow[nf*16] = (acc[mf][nf][r] - mean)*rs*lg[nf] + lb[nf];
    }
  }
}

extern "C" void kernel_launch(void* const* d_in, const int* in_sizes, int n_in,
                              void* d_out, int out_size, void* d_ws, size_t ws_size,
                              hipStream_t stream) {
  const float* x   = (const float*)d_in[0];
  const float* cw  = (const float*)d_in[1];
  const float* cb  = (const float*)d_in[2];
  const float* qw  = (const float*)d_in[3];
  const float* qb  = (const float*)d_in[4];
  const float* kw  = (const float*)d_in[5];
  const float* kb  = (const float*)d_in[6];
  const float* vw  = (const float*)d_in[7];
  const float* vb  = (const float*)d_in[8];
  const float* gw  = (const float*)d_in[9];
  const float* gb  = (const float*)d_in[10];
  const float* dec = (const float*)d_in[11];
  const float* l1g = (const float*)d_in[12];
  const float* l1b = (const float*)d_in[13];
  const float* w1  = (const float*)d_in[14];
  const float* b1  = (const float*)d_in[15];
  const float* w2  = (const float*)d_in[16];
  const float* b2  = (const float*)d_in[17];
  const float* l2g = (const float*)d_in[18];
  const float* l2b = (const float*)d_in[19];

  char* ws = (char*)d_ws;
  float* lam = (float*)(ws + OFF_LAM);
  bf16* wqt  = (bf16*)(ws + OFF_WQ);
  bf16* cwt  = (bf16*)(ws + OFF_CW);
  bf16* w1t  = (bf16*)(ws + OFF_W1T);
  bf16* w2t  = (bf16*)(ws + OFF_W2T);
  bf16* xc   = (bf16*)(ws + OFF_XC);
  bf16* q    = (bf16*)(ws + OFF_Q);
  bf16* u    = (bf16*)(ws + OFF_U);
  bf16* hbuf = (bf16*)(ws + OFF_H);
  bf16* ai   = (bf16*)(ws + OFF_AI);
  float* out = (float*)d_out;

  hipLaunchKernelGGL(k_prep_w,  dim3(1024), dim3(256), 0, stream, qw,kw,vw,gw,cw,w1,w2, wqt,cwt,w1t,w2t);
  hipLaunchKernelGGL(k_prep_lam,dim3(1),    dim3(384), 0, stream, dec, lam);
  hipLaunchKernelGGL(k_conv,    dim3(1536), dim3(256), 0, stream, x, cb, cwt, xc);
  hipLaunchKernelGGL(k_qkvg,    dim3(3072), dim3(512), 0, stream, xc, wqt, qb,kb,vb,gb, q, u);
  hipLaunchKernelGGL(k_scan,    dim3(256),  dim3(384), 0, stream, u, q, lam, l1g, l1b, hbuf);
  hipLaunchKernelGGL(k_mlp1,    dim3(1536), dim3(512), 0, stream, hbuf, w1t, b1, ai);
  hipLaunchKernelGGL(k_mlp2ln,  dim3(1024), dim3(512), 0, stream, ai, w2t, b2, x, l2g, l2b, out);
}

// Round 20
// 227.876 us; speedup vs baseline: 1.0853x; 1.0853x over previous
//
#include <hip/hip_runtime.h>
#include <hip/hip_bf16.h>

#define DIMD 384
#define SEQL 4096
#define NBATCH 8
#define NTOK (NBATCH*SEQL)

typedef float f32x4 __attribute__((ext_vector_type(4)));
typedef short s16x8 __attribute__((ext_vector_type(8)));
typedef unsigned short u16;
typedef __hip_bfloat16 bf16;

__device__ __forceinline__ float sigf(float x){ return 1.f/(1.f+__expf(-x)); }

// async global->LDS, 16B per lane. LDS dest must be wave-uniform base + lane*16.
typedef __attribute__((address_space(3))) void lds_void;
typedef const __attribute__((address_space(1))) void glb_void;
__device__ __forceinline__ void gl_lds16(const void* g, void* l) {
  __builtin_amdgcn_global_load_lds((glb_void*)g, (lds_void*)l, 16, 0, 0);
}

// ---------------- workspace layout (bytes) ----------------
#define OFF_LAM   0ul
#define OFF_WQ    4096ul                       // bf16 [1536][384]
#define OFF_CW    (OFF_WQ + 1179648ul)         // bf16 [384][448]
#define OFF_W1T   (OFF_CW + 344064ul)          // bf16 [768][384]
#define OFF_W2T   (OFF_W1T + 589824ul)         // bf16 [384][768]
#define OFF_XC    4194304ul                    // bf16 [32768][384]
#define OFF_Q     (OFF_XC + 25165824ul)        // bf16 [32768][384]
#define OFF_U     (OFF_XC + 50331648ul)        // bf16 [32768][384]
#define OFF_AI    OFF_U                        // bf16 [32768][768] (reuse after u dead)
#define OFF_H     (OFF_U + 50331648ul)         // bf16 [32768][384]
// total = 130,023,424 bytes

// ---------------- prep: weight transposes to [n][k] bf16 ----------------
__global__ void k_prep_w(const float* __restrict__ qw, const float* __restrict__ kw,
                         const float* __restrict__ vw, const float* __restrict__ gw,
                         const float* __restrict__ cw, const float* __restrict__ w1,
                         const float* __restrict__ w2,
                         bf16* __restrict__ wqt, bf16* __restrict__ cwt,
                         bf16* __restrict__ w1t, bf16* __restrict__ w2t) {
  const int total = 589824 + 172032 + 294912 + 294912;
  for (int j = blockIdx.x*blockDim.x + threadIdx.x; j < total; j += gridDim.x*blockDim.x) {
    if (j < 589824) {
      int n = j / 384, k = j % 384;
      int mat = n / 384;
      int np = n % 384;                        // (384 not pow2 -> %, not &)
      const float* W = (mat==0)?qw:(mat==1)?kw:(mat==2)?vw:gw;
      wqt[(size_t)n*384 + k] = __float2bfloat16(W[(size_t)k*384 + np]);
    } else if (j < 589824 + 172032) {
      int jj = j - 589824;
      int o = jj / 448, k = jj % 448;
      int kap = k >> 6, i = k & 63;
      cwt[(size_t)o*448 + k] = __float2bfloat16(cw[((size_t)o*64 + i)*7 + kap]);
    } else if (j < 589824 + 172032 + 294912) {
      int jj = j - (589824 + 172032);
      int n = jj / 384, k = jj % 384;
      w1t[(size_t)n*384 + k] = __float2bfloat16(w1[(size_t)k*768 + n]);
    } else {
      int jj = j - (589824 + 172032 + 294912);
      int n = jj / 768, k = jj % 768;
      w2t[(size_t)n*768 + k] = __float2bfloat16(w2[(size_t)k*384 + n]);
    }
  }
}

__global__ void k_prep_lam(const float* __restrict__ decay, float* __restrict__ lam) {
  __shared__ float red[6];
  int t = threadIdx.x; // 384 threads
  float v = sigf(decay[t]);
  for (int off = 32; off; off >>= 1) v += __shfl_xor(v, off, 64);
  if ((t & 63) == 0) red[t >> 6] = v;
  __syncthreads();
  if (t == 0) {
    float s = 0.f;
    for (int i = 0; i < 6; ++i) s += red[i];
    lam[0] = s * (1.f/384.f);
  }
}

// ---------------- grouped conv (k=7, groups=6) + silu -> xc bf16 ----------------
__global__ __launch_bounds__(256) void k_conv(const float* __restrict__ x, const float* __restrict__ cb,
                                              const bf16* __restrict__ cwt, bf16* __restrict__ xc) {
  int id = blockIdx.x;             // 1536 = 8 b * 32 st * 6 g
  int g = id % 6, st = (id/6) & 31, b = id / 192;
  int s0 = st * 128;
  __shared__ u16 xls[134*72];
  __shared__ u16 wls[64*456];
  int tid = threadIdx.x;
  for (int r0 = 0; r0 < 144; r0 += 16) {
    int row = r0 + (tid >> 4);
    if (row < 134) {
      int col = (tid & 15) * 4;
      int s = s0 - 3 + row;
      float4 v = make_float4(0.f,0.f,0.f,0.f);
      if (s >= 0 && s < SEQL)
        v = *reinterpret_cast<const float4*>(x + ((size_t)(b*SEQL + s))*DIMD + g*64 + col);
      u16* dst = &xls[row*72 + col];
      bf16 t0 = __float2bfloat16(v.x); dst[0] = *reinterpret_cast<u16*>(&t0);
      bf16 t1 = __float2bfloat16(v.y); dst[1] = *reinterpret_cast<u16*>(&t1);
      bf16 t2 = __float2bfloat16(v.z); dst[2] = *reinterpret_cast<u16*>(&t2);
      bf16 t3 = __float2bfloat16(v.w); dst[3] = *reinterpret_cast<u16*>(&t3);
    }
  }
  for (int i0 = 0; i0 < 28672; i0 += 1024) {
    int i = i0 + tid*4;
    int o = i / 448, k = i % 448;
    *reinterpret_cast<uint2*>(&wls[o*456 + k]) =
      *reinterpret_cast<const uint2*>(cwt + ((size_t)(g*64 + o))*448 + k);
  }
  __syncthreads();
  int w = tid >> 6, l = tid & 63, l15 = l & 15, lh = l >> 4;
  f32x4 zz = {0.f,0.f,0.f,0.f};
  f32x4 acc[2][4];
  for (int i=0;i<2;++i) for (int jn=0;jn<4;++jn) acc[i][jn]=zz;
  for (int kap = 0; kap < 7; ++kap) {
#pragma unroll
    for (int ic = 0; ic < 2; ++ic) {
      s16x8 a0 = *reinterpret_cast<const s16x8*>(&xls[(w*32 +  0 + l15 + kap)*72 + ic*32 + lh*8]);
      s16x8 a1 = *reinterpret_cast<const s16x8*>(&xls[(w*32 + 16 + l15 + kap)*72 + ic*32 + lh*8]);
#pragma unroll
      for (int nf = 0; nf < 4; ++nf) {
        s16x8 bfr = *reinterpret_cast<const s16x8*>(&wls[(nf*16 + l15)*456 + kap*64 + ic*32 + lh*8]);
        acc[0][nf] = __builtin_amdgcn_mfma_f32_16x16x32_bf16(a0, bfr, acc[0][nf], 0,0,0);
        acc[1][nf] = __builtin_amdgcn_mfma_f32_16x16x32_bf16(a1, bfr, acc[1][nf], 0,0,0);
      }
    }
  }
#pragma unroll
  for (int nf = 0; nf < 4; ++nf) {
    int ch = g*64 + nf*16 + l15;
    float bias = cb[ch];
#pragma unroll
    for (int mf = 0; mf < 2; ++mf) {
#pragma unroll
      for (int r = 0; r < 4; ++r) {
        int m = w*32 + mf*16 + lh*4 + r;
        float v = acc[mf][nf][r] + bias;
        v = v * sigf(v);
        xc[((size_t)(b*SEQL + s0 + m))*DIMD + ch] = __float2bfloat16(v);
      }
    }
  }
}

// ---------------- fused QKVG GEMM (R17): 8 waves, wave owns (matrix, 16-col half) ------------
__global__ __launch_bounds__(512) void k_qkvg(const bf16* __restrict__ xc, const bf16* __restrict__ wt,
    const float* __restrict__ qb, const float* __restrict__ kb,
    const float* __restrict__ vb, const float* __restrict__ gb,
    bf16* __restrict__ qout, bf16* __restrict__ uout) {
  int raw = blockIdx.x;                       // 3072
  int vv = (raw & 7)*384 + (raw >> 3);        // XCD swizzle
  int mt = vv / 12, ct = vv % 12;
  int m0 = mt*128, c0 = ct*32;
  __shared__ __align__(16) u16 smem[16384];   // 32KB dbuf 2x[128][64] / exchange overlay
  int tid = threadIdx.x, w = tid >> 6, l = tid & 63, l15 = l & 15, lh = l >> 4;
  int mat = w >> 1, ch0 = (w & 1)*16;         // wave's matrix + col-half
  f32x4 zz = {0.f,0.f,0.f,0.f};
  f32x4 acc[8];
#pragma unroll
  for (int i=0;i<8;++i) acc[i]=zz;
  const bf16* bp = wt + ((size_t)(mat*384 + c0 + ch0 + l15))*384 + lh*8;
  s16x8 bc0 = *reinterpret_cast<const s16x8*>(bp);
  s16x8 bc1 = *reinterpret_cast<const s16x8*>(bp + 32);
  s16x8 bn0, bn1;
#pragma unroll
  for (int p = 0; p < 2; ++p) {
    int off16 = p*512 + tid;
    int row = off16 >> 3, slot = off16 & 7;
    int ss = slot ^ (row & 7);
    gl_lds16(xc + ((size_t)(m0+row))*DIMD + ss*8, (char*)smem + off16*16);
  }
  __syncthreads();
  for (int kc = 0; kc < 6; ++kc) {
    const u16* cur = smem + (kc & 1)*8192;
    if (kc < 5) {
      char* nxt = (char*)(smem + ((kc & 1)^1)*8192);
#pragma unroll
      for (int p = 0; p < 2; ++p) {
        int off16 = p*512 + tid;
        int row = off16 >> 3, slot = off16 & 7;
        int ss = slot ^ (row & 7);
        gl_lds16(xc + ((size_t)(m0+row))*DIMD + (kc+1)*64 + ss*8, nxt + off16*16);
      }
      int nb = (kc+1)*64;
      bn0 = *reinterpret_cast<const s16x8*>(bp + nb);
      bn1 = *reinterpret_cast<const s16x8*>(bp + nb + 32);
    }
#pragma unroll
    for (int kk = 0; kk < 2; ++kk) {
      s16x8 curb = kk ? bc1 : bc0;
#pragma unroll
      for (int mf = 0; mf < 8; ++mf) {
        s16x8 af = *reinterpret_cast<const s16x8*>(
            &cur[(mf*16 + l15)*64 + (((kk*4 + lh) ^ (l15 & 7))*8)]);
        acc[mf] = __builtin_amdgcn_mfma_f32_16x16x32_bf16(af, curb, acc[mf], 0,0,0);
      }
    }
    __syncthreads();
    bc0 = bn0; bc1 = bn1;
  }
  const float* bpv = (mat==0)?qb:(mat==1)?kb:(mat==2)?vb:gb;
  float bias = bpv[c0 + ch0 + l15];
  if (mat == 0) {
#pragma unroll
    for (int mf=0;mf<8;++mf)
#pragma unroll
      for (int r=0;r<4;++r) {
        int m = mf*16 + lh*4 + r, c = ch0 + l15;
        qout[((size_t)(m0+m))*DIMD + c0 + c] = __float2bfloat16(acc[mf][r] + bias);
      }
  } else {
    u16* exm = smem + (size_t)(mat-1)*(128*40);
#pragma unroll
    for (int mf=0;mf<8;++mf)
#pragma unroll
      for (int r=0;r<4;++r) {
        int m = mf*16 + lh*4 + r, c = ch0 + l15;
        bf16 t = __float2bfloat16(acc[mf][r] + bias);
        exm[m*40 + c] = *reinterpret_cast<u16*>(&t);
      }
  }
  __syncthreads();
#pragma unroll
  for (int p = 0; p < 8; ++p) {
    int idx = p*512 + tid;
    int m = idx >> 5, c = idx & 31;
    u16 kr = smem[0*(128*40) + m*40 + c];
    u16 vr = smem[1*(128*40) + m*40 + c];
    u16 gr = smem[2*(128*40) + m*40 + c];
    float kvv = __bfloat162float(*reinterpret_cast<bf16*>(&kr));
    float vvv = __bfloat162float(*reinterpret_cast<bf16*>(&vr));
    float gvv = __bfloat162float(*reinterpret_cast<bf16*>(&gr));
    uout[((size_t)(m0+m))*DIMD + c0 + c] = __float2bfloat16(vvv * sigf(gvv) * kvv);
  }
}

// ---------------- decayed cumsum + q*diag + LN1 -> h bf16 (48KB LDS, 3 blocks/CU) -------------
__global__ __launch_bounds__(384) void k_scan(const bf16* __restrict__ u, const bf16* __restrict__ q,
    const float* __restrict__ lam_p, const float* __restrict__ l1g, const float* __restrict__ l1b,
    bf16* __restrict__ h) {
  int b = blockIdx.x >> 5, c = blockIdx.x & 31; // 8 x 32
  int d = threadIdx.x;                          // 384
  float lam = lam_p[0];
  __shared__ float ols[32*384];                 // 48 KB
  __shared__ float lgs[384], lbs[384];
  lgs[d] = l1g[d]; lbs[d] = l1b[d];
  int s0 = c*128;
  size_t base = ((size_t)b*SEQL)*DIMD + d;
  float carry = 0.f;
  int sstart = s0 - 64; if (sstart < 0) sstart = 0;
  for (int s = sstart; s < s0; s += 8) {
    float uv[8];
#pragma unroll
    for (int j = 0; j < 8; ++j) uv[j] = __bfloat162float(u[base + (size_t)(s+j)*DIMD]);
#pragma unroll
    for (int j = 0; j < 8; ++j) carry = carry*lam + uv[j];
  }
  int w = d >> 6, lane = d & 63;
  for (int p = 0; p < 4; ++p) {
    int sb = s0 + p*32;
    __syncthreads();
    for (int it0 = 0; it0 < 32; it0 += 8) {
      float uv[8], qv[8];
#pragma unroll
      for (int j = 0; j < 8; ++j) uv[j] = __bfloat162float(u[base + (size_t)(sb+it0+j)*DIMD]);
#pragma unroll
      for (int j = 0; j < 8; ++j) qv[j] = __bfloat162float(q[base + (size_t)(sb+it0+j)*DIMD]);
#pragma unroll
      for (int j = 0; j < 8; ++j) {
        carry = carry*lam + uv[j];
        ols[(it0+j)*384 + d] = carry * qv[j];
      }
    }
    __syncthreads();
    for (int t = w; t < 32; t += 6) {
      float vv[6]; float s1 = 0.f, s2 = 0.f;
#pragma unroll
      for (int j = 0; j < 6; ++j) {
        vv[j] = ols[t*384 + j*64 + lane];
        s1 += vv[j]; s2 += vv[j]*vv[j];
      }
      for (int off = 32; off; off >>= 1) { s1 += __shfl_xor(s1, off, 64); s2 += __shfl_xor(s2, off, 64); }
      float mean = s1 * (1.f/384.f);
      float var = s2 * (1.f/384.f) - mean*mean;
      float rs = rsqrtf(var + 1e-5f);
      size_t rowo = ((size_t)(b*SEQL + sb + t))*DIMD;
#pragma unroll
      for (int j = 0; j < 6; ++j) {
        int dd = j*64 + lane;
        h[rowo + dd] = __float2bfloat16((vv[j]-mean)*rs*lgs[dd] + lbs[dd]);
      }
    }
  }
}

// ---------------- MLP GEMM1 + silu -> ai bf16 (T3 stage-ahead dbuf, BK=64) --------------
__global__ __launch_bounds__(512) void k_mlp1(const bf16* __restrict__ h, const bf16* __restrict__ w1t,
                                              const float* __restrict__ b1, bf16* __restrict__ ai) {
  int raw = blockIdx.x;                 // 1536
  int vv = (raw & 7)*192 + (raw >> 3);
  int mt = vv / 6, nt = vv % 6;
  int m0 = mt*128, n0 = nt*128;
  __shared__ __align__(16) u16 als[16384];   // 32KB = 2 x [128][64]
  int tid = threadIdx.x, w = tid >> 6, l = tid & 63, l15 = l & 15, lh = l >> 4;
  int wm = (w >> 2)*64, wn = (w & 3)*32;
  f32x4 zz = {0.f,0.f,0.f,0.f};
  f32x4 acc[4][2];
#pragma unroll
  for (int i=0;i<4;++i) for (int jn=0;jn<2;++jn) acc[i][jn]=zz;
  const bf16* bp0 = w1t + ((size_t)(n0 + wn + l15))*384 + lh*8;
  s16x8 bA[2], bB[2];
#pragma unroll
  for (int nf = 0; nf < 2; ++nf)
    bA[nf] = *reinterpret_cast<const s16x8*>(bp0 + (size_t)nf*16*384);
#pragma unroll
  for (int p = 0; p < 2; ++p) {
    int off16 = p*512 + tid;
    int row = off16 >> 3, slot = off16 & 7;
    int ss = slot ^ (row & 7);
    gl_lds16(h + ((size_t)(m0+row))*DIMD + ss*8, (char*)als + off16*16);
  }
  __syncthreads();
  for (int kc = 0; kc < 6; ++kc) {
    const u16* cur = als + (kc & 1)*8192;
    if (kc < 5) {
      char* nxt = (char*)(als + ((kc & 1)^1)*8192);
#pragma unroll
      for (int p = 0; p < 2; ++p) {
        int off16 = p*512 + tid;
        int row = off16 >> 3, slot = off16 & 7;
        int ss = slot ^ (row & 7);
        gl_lds16(h + ((size_t)(m0+row))*DIMD + (kc+1)*64 + ss*8, nxt + off16*16);
      }
    }
#pragma unroll
    for (int kk = 0; kk < 2; ++kk) {
      int nko = (kk == 0) ? (kc*64 + 32) : ((kc < 5) ? (kc+1)*64 : -1);
      if (nko >= 0) {
        if (kk) {
#pragma unroll
          for (int nf = 0; nf < 2; ++nf)
            bA[nf] = *reinterpret_cast<const s16x8*>(bp0 + (size_t)nf*16*384 + nko);
        } else {
#pragma unroll
          for (int nf = 0; nf < 2; ++nf)
            bB[nf] = *reinterpret_cast<const s16x8*>(bp0 + (size_t)nf*16*384 + nko);
        }
      }
#pragma unroll
      for (int mf = 0; mf < 4; ++mf) {
        s16x8 af = *reinterpret_cast<const s16x8*>(
            &cur[(wm + mf*16 + l15)*64 + (((kk*4 + lh) ^ (l15 & 7))*8)]);
#pragma unroll
        for (int nf = 0; nf < 2; ++nf)
          acc[mf][nf] = __builtin_amdgcn_mfma_f32_16x16x32_bf16(
              af, kk ? bB[nf] : bA[nf], acc[mf][nf], 0,0,0);
      }
    }
    __syncthreads();
  }
  float bias[2];
#pragma unroll
  for (int nf = 0; nf < 2; ++nf) bias[nf] = b1[n0 + wn + nf*16 + l15];
#pragma unroll
  for (int mf = 0; mf < 4; ++mf)
#pragma unroll
    for (int nf = 0; nf < 2; ++nf)
#pragma unroll
      for (int r = 0; r < 4; ++r) {
        int m = wm + mf*16 + lh*4 + r, ch = n0 + wn + nf*16 + l15;
        float v = acc[mf][nf][r] + bias[nf];
        v = v * sigf(v);
        ai[(size_t)(m0+m)*768 + ch] = __float2bfloat16(v);
      }
}

// ---------------- fused MLP GEMM2 + bias + residual + LN2 -> out f32 (R18: x issue-early) -----
// 512 threads (8 waves), M=64/block, grid 512. Wave w owns cols [w*48, w*48+48).
// x residual prefetched into 48 regs right after the prologue barrier (T14).
__global__ __launch_bounds__(512) void k_mlp2ln(const bf16* __restrict__ ai, const bf16* __restrict__ w2t,
                                                const float* __restrict__ b2, const float* __restrict__ x,
                                                const float* __restrict__ l2g, const float* __restrict__ l2b,
                                                float* __restrict__ out) {
  int raw = blockIdx.x;                 // 512
  int mt = (raw & 7)*64 + (raw >> 3);   // XCD swizzle
  int m0 = mt*64;
  __shared__ __align__(16) u16 als[16384];    // 32KB = 2 x [64][128]
  __shared__ float pls[8][64][2];             // per-wave row partials (4KB)
  int tid = threadIdx.x, w = tid >> 6, l = tid & 63, l15 = l & 15, lh = l >> 4;
  int wn = w*48;
  f32x4 zz = {0.f,0.f,0.f,0.f};
  f32x4 acc[4][3];
#pragma unroll
  for (int i=0;i<4;++i)
#pragma unroll
    for (int jn=0;jn<3;++jn) acc[i][jn]=zz;
  const bf16* bp0 = w2t + ((size_t)(wn + l15))*768 + lh*8;
  s16x8 bA[3], bB[3];
#pragma unroll
  for (int nf = 0; nf < 3; ++nf)
    bA[nf] = *reinterpret_cast<const s16x8*>(bp0 + (size_t)nf*16*768);
  // prologue: tile 0 -> buf0
#pragma unroll
  for (int p = 0; p < 2; ++p) {
    int off16 = p*512 + tid;
    int row = off16 >> 4, slot = off16 & 15;
    int ss = slot ^ (row & 7);
    gl_lds16(ai + ((size_t)(m0+row))*768 + ss*8, (char*)als + off16*16);
  }
  __syncthreads();
  // x issue-early: 48 scattered f32 loads; drained by kc=0's end barrier (full phase of cover)
  float xpre[4][4][3];
#pragma unroll
  for (int mf = 0; mf < 4; ++mf)
#pragma unroll
    for (int r = 0; r < 4; ++r) {
      int m = mf*16 + lh*4 + r;
      const float* xr = x + (size_t)(m0+m)*DIMD + wn + l15;
#pragma unroll
      for (int nf = 0; nf < 3; ++nf) xpre[mf][r][nf] = xr[nf*16];
    }
  for (int kc = 0; kc < 6; ++kc) {
    const u16* cur = als + (kc & 1)*8192;
    if (kc < 5) {
      char* nxt = (char*)(als + ((kc & 1)^1)*8192);
#pragma unroll
      for (int p = 0; p < 2; ++p) {
        int off16 = p*512 + tid;
        int row = off16 >> 4, slot = off16 & 15;
        int ss = slot ^ (row & 7);
        gl_lds16(ai + ((size_t)(m0+row))*768 + (kc+1)*128 + ss*8, nxt + off16*16);
      }
    }
#pragma unroll
    for (int kk = 0; kk < 4; ++kk) {
      int nko = (kk < 3) ? (kc*128 + (kk+1)*32) : ((kc < 5) ? (kc+1)*128 : -1);
      if (nko >= 0) {
        if (kk & 1) {
#pragma unroll
          for (int nf = 0; nf < 3; ++nf)
            bA[nf] = *reinterpret_cast<const s16x8*>(bp0 + (size_t)nf*16*768 + nko);
        } else {
#pragma unroll
          for (int nf = 0; nf < 3; ++nf)
            bB[nf] = *reinterpret_cast<const s16x8*>(bp0 + (size_t)nf*16*768 + nko);
        }
      }
#pragma unroll
      for (int mf = 0; mf < 4; ++mf) {
        s16x8 af = *reinterpret_cast<const s16x8*>(
            &cur[(mf*16 + l15)*128 + (((kk*4 + lh) ^ (l15 & 7))*8)]);
#pragma unroll
        for (int nf = 0; nf < 3; ++nf)
          acc[mf][nf] = __builtin_amdgcn_mfma_f32_16x16x32_bf16(
              af, (kk & 1) ? bB[nf] : bA[nf], acc[mf][nf], 0,0,0);
      }
    }
    __syncthreads();
  }
  // epilogue: v = acc + b2 + xpre (in regs), row stats, LN, store
  float bias[3];
#pragma unroll
  for (int nf = 0; nf < 3; ++nf) bias[nf] = b2[wn + nf*16 + l15];
#pragma unroll
  for (int mf = 0; mf < 4; ++mf) {
#pragma unroll
    for (int r = 0; r < 4; ++r) {
      int m = mf*16 + lh*4 + r;
      float sa = 0.f, sb = 0.f;
#pragma unroll
      for (int nf = 0; nf < 3; ++nf) {
        float v = acc[mf][nf][r] + bias[nf] + xpre[mf][r][nf];
        acc[mf][nf][r] = v;
        sa += v; sb += v*v;
      }
#pragma unroll
      for (int off = 1; off < 16; off <<= 1) {
        sa += __shfl_xor(sa, off, 16);
        sb += __shfl_xor(sb, off, 16);
      }
      if (l15 == 0) { pls[w][m][0] = sa; pls[w][m][1] = sb; }
    }
  }
  __syncthreads();
  float lg[3], lb[3];
#pragma unroll
  for (int nf = 0; nf < 3; ++nf) { lg[nf] = l2g[wn + nf*16 + l15]; lb[nf] = l2b[wn + nf*16 + l15]; }
#pragma unroll
  for (int mf = 0; mf < 4; ++mf) {
#pragma unroll
    for (int r = 0; r < 4; ++r) {
      int m = mf*16 + lh*4 + r;
      float S1 = 0.f, S2 = 0.f;
#pragma unroll
      for (int ww = 0; ww < 8; ++ww) { S1 += pls[ww][m][0]; S2 += pls[ww][m][1]; }
      float mean = S1 * (1.f/384.f);
      float var = S2 * (1.f/384.f) - mean*mean;
      float rs = rsqrtf(var + 1e-5f);
      float* orow = out + (size_t)(m0+m)*DIMD + wn + l15;
#pragma unroll
      for (int nf = 0; nf < 3; ++nf)
        orow[nf*16] = (acc[mf][nf][r] - mean)*rs*lg[nf] + lb[nf];
    }
  }
}

extern "C" void kernel_launch(void* const* d_in, const int* in_sizes, int n_in,
                              void* d_out, int out_size, void* d_ws, size_t ws_size,
                              hipStream_t stream) {
  const float* x   = (const float*)d_in[0];
  const float* cw  = (const float*)d_in[1];
  const float* cb  = (const float*)d_in[2];
  const float* qw  = (const float*)d_in[3];
  const float* qb  = (const float*)d_in[4];
  const float* kw  = (const float*)d_in[5];
  const float* kb  = (const float*)d_in[6];
  const float* vw  = (const float*)d_in[7];
  const float* vb  = (const float*)d_in[8];
  const float* gw  = (const float*)d_in[9];
  const float* gb  = (const float*)d_in[10];
  const float* dec = (const float*)d_in[11];
  const float* l1g = (const float*)d_in[12];
  const float* l1b = (const float*)d_in[13];
  const float* w1  = (const float*)d_in[14];
  const float* b1  = (const float*)d_in[15];
  const float* w2  = (const float*)d_in[16];
  const float* b2  = (const float*)d_in[17];
  const float* l2g = (const float*)d_in[18];
  const float* l2b = (const float*)d_in[19];

  char* ws = (char*)d_ws;
  float* lam = (float*)(ws + OFF_LAM);
  bf16* wqt  = (bf16*)(ws + OFF_WQ);
  bf16* cwt  = (bf16*)(ws + OFF_CW);
  bf16* w1t  = (bf16*)(ws + OFF_W1T);
  bf16* w2t  = (bf16*)(ws + OFF_W2T);
  bf16* xc   = (bf16*)(ws + OFF_XC);
  bf16* q    = (bf16*)(ws + OFF_Q);
  bf16* u    = (bf16*)(ws + OFF_U);
  bf16* hbuf = (bf16*)(ws + OFF_H);
  bf16* ai   = (bf16*)(ws + OFF_AI);
  float* out = (float*)d_out;

  hipLaunchKernelGGL(k_prep_w,  dim3(1024), dim3(256), 0, stream, qw,kw,vw,gw,cw,w1,w2, wqt,cwt,w1t,w2t);
  hipLaunchKernelGGL(k_prep_lam,dim3(1),    dim3(384), 0, stream, dec, lam);
  hipLaunchKernelGGL(k_conv,    dim3(1536), dim3(256), 0, stream, x, cb, cwt, xc);
  hipLaunchKernelGGL(k_qkvg,    dim3(3072), dim3(512), 0, stream, xc, wqt, qb,kb,vb,gb, q, u);
  hipLaunchKernelGGL(k_scan,    dim3(256),  dim3(384), 0, stream, u, q, lam, l1g, l1b, hbuf);
  hipLaunchKernelGGL(k_mlp1,    dim3(1536), dim3(512), 0, stream, hbuf, w1t, b1, ai);
  hipLaunchKernelGGL(k_mlp2ln,  dim3(512),  dim3(512), 0, stream, ai, w2t, b2, x, l2g, l2b, out);
}